// Round 8
// baseline (290.399 us; speedup 1.0000x reference)
//
#include <hip/hip_runtime.h>
#include <hip/hip_bf16.h>

#define NN 8192
#define NHEADS 4
#define OUTF 64
#define NCHUNK 4
#define CHUNK 2048
#define ROWS 32
#define LOG2E 1.4426950408889634f

typedef __bf16 bf16x8 __attribute__((ext_vector_type(8)));
typedef float fx4 __attribute__((ext_vector_type(4)));
typedef unsigned short ushort8 __attribute__((ext_vector_type(8)));

// ---------------------------------------------------------------------------
// Kernel 0 (fused prep): blocks [0,2048) stream adj -> bitmask (BW-bound);
// blocks [2048,2560) compute Wh/R/F1/F2/whsw (compute-bound, LDS-free so the
// two kinds co-schedule). The Wh blocks hide inside the adj stream's time.
// ---------------------------------------------------------------------------
__global__ __launch_bounds__(256) void k_prep(
    const int* __restrict__ adj, unsigned* __restrict__ bm,
    const float* __restrict__ h, const float* __restrict__ W,
    const float* __restrict__ a1, const float* __restrict__ a2,
    unsigned short* __restrict__ whsw, float* __restrict__ R,
    float* __restrict__ F1, float* __restrict__ F2)
{
  const int tid = threadIdx.x;
  const int bx = blockIdx.x;
  if (bx < 2048) {
    // ---- adj (256 MB) -> packed bitmask (8 MB), read exactly once ----
    const int lane = tid & 63;
    const int row = bx * 4 + (tid >> 6);
    const int* ap = adj + (size_t)row * NN;
    unsigned* bp = bm + (size_t)row * (NN / 32);
    for (int it8 = 0; it8 < 16; ++it8) {
      int v[8];
#pragma unroll
      for (int u = 0; u < 8; ++u)
        v[u] = ap[(it8 * 8 + u) * 64 + lane];
#pragma unroll
      for (int u = 0; u < 8; ++u) {
        unsigned long long m = __ballot(v[u] != 0);
        unsigned word = (lane == 1) ? (unsigned)(m >> 32) : (unsigned)m;
        if (lane < 2) bp[(it8 * 8 + u) * 2 + lane] = word;
      }
    }
    return;
  }

  // ---- Wh part: Wh = h @ W[hd]; emit R/F1/F2 + swizzled bf16 Wh^T ----
  const int b = bx - 2048;
  const int hd = b >> 7;
  const int i0 = (b & 127) << 6;            // 64 rows per block
  const int w = tid >> 6, o = tid & 63;     // wave w: rows ibase..+15, col o
  const int ibase = i0 + w * 16;

  float acc[16];
#pragma unroll
  for (int m = 0; m < 16; ++m) acc[m] = 0.f;

  const float* hp = h + (size_t)ibase * 256;
  const float* Wp = W + hd * (256 * 64) + o;   // W[k][o], stride 64
  for (int k4 = 0; k4 < 64; ++k4) {
    float w0 = Wp[(k4 * 4 + 0) * 64];
    float w1 = Wp[(k4 * 4 + 1) * 64];
    float w2 = Wp[(k4 * 4 + 2) * 64];
    float w3 = Wp[(k4 * 4 + 3) * 64];
#pragma unroll
    for (int m = 0; m < 16; ++m) {
      fx4 hv = *(const fx4*)(hp + m * 256 + k4 * 4);
      acc[m] += hv[0] * w0 + hv[1] * w1 + hv[2] * w2 + hv[3] * w3;
    }
  }

  const float a1v = a1[hd * 64 + o], a2v = a2[hd * 64 + o];
#pragma unroll
  for (int m = 0; m < 16; ++m) {
    float s1 = acc[m] * a1v, s2 = acc[m] * a2v;
#pragma unroll
    for (int d = 1; d < 64; d <<= 1) {
      s1 += __shfl_xor(s1, d);
      s2 += __shfl_xor(s2, d);
    }
    if (o == 0) {
      int ix = hd * NN + ibase + m;
      R[ix]  = __builtin_amdgcn_exp2f(-0.8f * s1 * LOG2E);
      F1[ix] = __builtin_amdgcn_exp2f(s2 * LOG2E);
      F2[ix] = __builtin_amdgcn_exp2f(0.2f * s2 * LOG2E);
    }
  }

  // swizzled bf16 store of Wh (rows ibase..+15, col o)
  size_t base = (size_t)hd * 524288 + (size_t)((i0 >> 5) + (w >> 1)) * 2048 +
                (size_t)(o >> 4) * 512;
  int ln0 = (o & 15) + 16 * ((w & 1) * 2);
  ushort8 pk0, pk1;
#pragma unroll
  for (int m = 0; m < 8; ++m) {
    pk0[m] = __builtin_bit_cast(unsigned short, (__bf16)acc[m]);
    pk1[m] = __builtin_bit_cast(unsigned short, (__bf16)acc[m + 8]);
  }
  *(ushort8*)(whsw + base + (size_t)ln0 * 8) = pk0;
  *(ushort8*)(whsw + base + (size_t)(ln0 + 16) * 8) = pk1;
}

// ---------------------------------------------------------------------------
// Kernel 2: masked unnormalized softmax + PV MFMA (no adj stream here).
// Grid: 1024 blocks = 256 row-tiles (32 rows) x 4 j-chunks (2048).
// ci = (bx&7)>>1 -> each XCD pair owns one chunk: 1 MiB whsw + 2 MB bm slice,
// L2-resident. 4 waves = 4 heads, 2 rowsets of 16 rows per wave (low VGPR ->
// 4 waves/SIMD). bml padded [w*33+r]: transpose stage AND reads conflict-free.
// q = max(F1_j, r_i*F2_j) masked; rowsum via a 5th MFMA (all-ones B).
// ---------------------------------------------------------------------------
struct Tile {
  fx4 f1a, f1b, f2a, f2b;   // F1/F2 slices (per lane group g)
  bf16x8 b0, b1, b2, b3;    // Wh^T B-fragments
  unsigned m0, m1;          // bitmask words for rowsets 0/1
};

__device__ __forceinline__ void load_tile(Tile& t, const float* F1p,
                                          const float* F2p,
                                          const unsigned short* wp,
                                          const unsigned* bml, int il, int jb)
{
  t.f1a = *(const fx4*)(F1p + jb);
  t.f1b = *(const fx4*)(F1p + jb + 4);
  t.f2a = *(const fx4*)(F2p + jb);
  t.f2b = *(const fx4*)(F2p + jb + 4);
  const unsigned short* wq = wp + (size_t)(jb >> 5) * 2048;
  t.b0 = *(const bf16x8*)(wq);
  t.b1 = *(const bf16x8*)(wq + 512);
  t.b2 = *(const bf16x8*)(wq + 1024);
  t.b3 = *(const bf16x8*)(wq + 1536);
  const unsigned* mb = bml + (jb >> 5) * 33;
  t.m0 = mb[il];
  t.m1 = mb[16 + il];
}

__device__ __forceinline__ void compute_tile(const Tile& t, const float* Rr,
                                             int g, const bf16x8& ones,
                                             fx4 acc[2][4], fx4* accS)
{
#pragma unroll
  for (int rs = 0; rs < 2; ++rs) {
    unsigned sm = (rs ? t.m1 : t.m0) >> (g * 8);
    float p[8];
#pragma unroll
    for (int e = 0; e < 8; ++e) {
      float f1 = (e < 4) ? t.f1a[e] : t.f1b[e - 4];
      float f2 = (e < 4) ? t.f2a[e] : t.f2b[e - 4];
      float pm = fmaxf(f1, Rr[rs] * f2);   // ∝ exp(leakyrelu(es+ed))
      unsigned keep = (unsigned)(((int)(sm << (31 - e))) >> 31);  // bfe_i32
      p[e] = __builtin_bit_cast(float,
                 __builtin_bit_cast(unsigned, pm) & keep);
    }
    bf16x8 af;
#pragma unroll
    for (int e = 0; e < 8; ++e) af[e] = (__bf16)p[e];
    acc[rs][0] = __builtin_amdgcn_mfma_f32_16x16x32_bf16(af, t.b0, acc[rs][0], 0, 0, 0);
    acc[rs][1] = __builtin_amdgcn_mfma_f32_16x16x32_bf16(af, t.b1, acc[rs][1], 0, 0, 0);
    acc[rs][2] = __builtin_amdgcn_mfma_f32_16x16x32_bf16(af, t.b2, acc[rs][2], 0, 0, 0);
    acc[rs][3] = __builtin_amdgcn_mfma_f32_16x16x32_bf16(af, t.b3, acc[rs][3], 0, 0, 0);
    accS[rs] = __builtin_amdgcn_mfma_f32_16x16x32_bf16(af, ones, accS[rs], 0, 0, 0);
  }
}

__global__ __launch_bounds__(256) void k_attn(
    const unsigned* __restrict__ bm, const unsigned short* __restrict__ whsw,
    const float* __restrict__ Rg, const float* __restrict__ F1g,
    const float* __restrict__ F2g, float* __restrict__ pacc,
    float* __restrict__ psum)
{
  __shared__ unsigned bml[(CHUNK / 32) * 33];   // padded [jw*33+row]: 8.25 KiB
  const int tid = threadIdx.x;
  const int lane = tid & 63;
  const int hd = tid >> 6;                 // wave = head
  const int bx = blockIdx.x;
  const int xcd = bx & 7;
  const int ci = xcd >> 1;                 // chunk pinned to an XCD pair
  const int rt = ((bx >> 3) << 1) | (xcd & 1);
  const int i0 = rt << 5;                  // 32 rows
  const int j0 = ci * CHUNK;
  const int il = lane & 15;
  const int g = lane >> 4;

  // ---- stage bitmask slice (8 KB) into LDS; pad 33 -> conflict-free both ways
  for (int it = 0; it < 8; ++it) {
    int idx = it * 256 + tid;              // 2048 words
    int r = idx >> 6, w = idx & 63;        // w = lane -> coalesced global read
    unsigned v = bm[(size_t)(i0 + r) * (NN / 32) + (j0 >> 5) + w];
    bml[w * 33 + r] = v;                   // banks (w+r)%32: all distinct
  }
  __syncthreads();

  // ---- masked softmax + PV ----
  float Rr[2];
#pragma unroll
  for (int rs = 0; rs < 2; ++rs)
    Rr[rs] = Rg[hd * NN + i0 + rs * 16 + il];
  const float* F1p = F1g + hd * NN + j0 + g * 8;
  const float* F2p = F2g + hd * NN + j0 + g * 8;
  const unsigned short* wp = whsw + (size_t)hd * 524288 +
                             (size_t)(j0 >> 5) * 2048 + (size_t)lane * 8;
  bf16x8 ones;
#pragma unroll
  for (int e = 0; e < 8; ++e) ones[e] = (__bf16)1.0f;

  fx4 acc[2][4] = {};
  fx4 accS[2] = {};

  Tile t0, t1;
  load_tile(t0, F1p, F2p, wp, bml, il, 0);
  for (int jb = 0; jb < CHUNK; jb += 64) {
    load_tile(t1, F1p, F2p, wp, bml, il, jb + 32);
    compute_tile(t0, Rr, g, ones, acc, accS);
    if (jb + 64 < CHUNK) load_tile(t0, F1p, F2p, wp, bml, il, jb + 64);
    compute_tile(t1, Rr, g, ones, acc, accS);
  }

  // partial row sums (all columns of accS equal the rowsum)
#pragma unroll
  for (int rs = 0; rs < 2; ++rs) {
    if (il == 0) {
#pragma unroll
      for (int r = 0; r < 4; ++r)
        psum[(size_t)(ci * NHEADS + hd) * NN + i0 + rs * 16 + g * 4 + r] =
            accS[rs][r];
    }
  }

  // raw accumulator store. C/D: col f = lane&15, row i = 4*(lane>>4)+r
  float* pc = pacc + (size_t)ci * NN * 256;
#pragma unroll
  for (int rs = 0; rs < 2; ++rs)
#pragma unroll
    for (int r = 0; r < 4; ++r)
#pragma unroll
      for (int ft = 0; ft < 4; ++ft)
        pc[(size_t)(i0 + rs * 16 + g * 4 + r) * 256 + hd * 64 + ft * 16 + il] =
            acc[rs][ft][r];
}

// ---------------------------------------------------------------------------
// Kernel 3: combine chunks -> normalize -> ELU -> out = att @ fc_w^T + fc_b
// 256 blocks x 32 rows.
// ---------------------------------------------------------------------------
__global__ __launch_bounds__(256) void k_fc(
    const float* __restrict__ pacc, const float* __restrict__ psum,
    const float* __restrict__ fcw, const float* __restrict__ fcb,
    float* __restrict__ out)
{
  __shared__ float ws[256 * 65];    // fcw transposed: ws[c*65 + o]
  __shared__ float ash[32 * 260];   // combined att rows
  __shared__ float inv[32 * 4];
  const int tid = threadIdx.x;
  const int i0 = blockIdx.x * 32;

  for (int idx = tid; idx < 64 * 256; idx += 256) {
    int o = idx >> 8, c = idx & 255;
    ws[c * 65 + o] = fcw[idx];
  }
  if (tid < 128) {
    int m = tid >> 2, hh = tid & 3;
    float s = 0.f;
#pragma unroll
    for (int ci = 0; ci < NCHUNK; ++ci)
      s += psum[(size_t)(ci * NHEADS + hh) * NN + i0 + m];
    inv[m * 4 + hh] = 1.0f / s;
  }
  __syncthreads();

  for (int idx = tid; idx < 32 * 64; idx += 256) {
    int m = idx >> 6, q = idx & 63;
    int hh = q >> 4;
    size_t off = (size_t)(i0 + m) * 256 + q * 4;
    fx4 v = {};
#pragma unroll
    for (int ci = 0; ci < NCHUNK; ++ci) {
      fx4 a = *(const fx4*)(pacc + (size_t)ci * NN * 256 + off);
      v[0] += a[0]; v[1] += a[1]; v[2] += a[2]; v[3] += a[3];
    }
    float iv = inv[m * 4 + hh];
#pragma unroll
    for (int j = 0; j < 4; ++j) {
      float x = v[j] * iv;
      x = (x > 0.f) ? x : (__builtin_amdgcn_exp2f(x * LOG2E) - 1.0f);  // ELU
      ash[m * 260 + q * 4 + j] = x;
    }
  }
  __syncthreads();

  const int w = tid >> 6, o = tid & 63;
  float acc[8];
#pragma unroll
  for (int m = 0; m < 8; ++m) acc[m] = 0.f;

  for (int c4 = 0; c4 < 64; ++c4) {
    float w0 = ws[(c4 * 4 + 0) * 65 + o];
    float w1 = ws[(c4 * 4 + 1) * 65 + o];
    float w2 = ws[(c4 * 4 + 2) * 65 + o];
    float w3 = ws[(c4 * 4 + 3) * 65 + o];
#pragma unroll
    for (int m = 0; m < 8; ++m) {
      fx4 hv = *(const fx4*)(&ash[(w * 8 + m) * 260 + c4 * 4]);
      acc[m] += hv[0] * w0 + hv[1] * w1 + hv[2] * w2 + hv[3] * w3;
    }
  }
  const float bo = fcb[o];
#pragma unroll
  for (int m = 0; m < 8; ++m)
    out[(size_t)(i0 + w * 8 + m) * 64 + o] = acc[m] + bo;
}

extern "C" void kernel_launch(void* const* d_in, const int* in_sizes, int n_in,
                              void* d_out, int out_size, void* d_ws, size_t ws_size,
                              hipStream_t stream) {
  (void)in_sizes; (void)n_in; (void)out_size; (void)ws_size;
  const float* h   = (const float*)d_in[0];
  const int*   adj = (const int*)d_in[1];
  const float* W   = (const float*)d_in[2];
  const float* a1  = (const float*)d_in[3];
  const float* a2  = (const float*)d_in[4];
  const float* fcw = (const float*)d_in[5];
  const float* fcb = (const float*)d_in[6];
  float* out = (float*)d_out;

  char* base = (char*)d_ws;
  unsigned short* whsw = (unsigned short*)base;            // 4 MiB
  float* R  = (float*)(base + (4u << 20));                 // 128 KiB each
  float* F1 = (float*)(base + (4u << 20) + (128u << 10));
  float* F2 = (float*)(base + (4u << 20) + (256u << 10));
  unsigned* bmask = (unsigned*)(base + (5u << 20));        // 8 MiB
  float* pacc = (float*)(base + (13u << 20));              // 32 MiB
  float* psum = (float*)(base + (45u << 20));              // 512 KiB

  k_prep<<<dim3(2560), dim3(256), 0, stream>>>(adj, bmask, h, W, a1, a2,
                                               whsw, R, F1, F2);
  k_attn<<<dim3(1024), dim3(256), 0, stream>>>(bmask, whsw, R, F1, F2, pacc, psum);
  k_fc<<<dim3(256), dim3(256), 0, stream>>>(pacc, psum, fcw, fcb, out);
}

// Round 9
// 222.664 us; speedup vs baseline: 1.3042x; 1.3042x over previous
//
#include <hip/hip_runtime.h>
#include <hip/hip_bf16.h>

#define NN 8192
#define NHEADS 4
#define OUTF 64
#define NCHUNK 4
#define CHUNK 2048
#define ROWS 32
#define NWH 512
#define LOG2E 1.4426950408889634f

typedef __bf16 bf16x8 __attribute__((ext_vector_type(8)));
typedef float fx4 __attribute__((ext_vector_type(4)));
typedef int ix4 __attribute__((ext_vector_type(4)));
typedef unsigned short ushort8 __attribute__((ext_vector_type(8)));

// ---------------------------------------------------------------------------
// Kernel 0 (fused prep).
// Blocks [0,NWH): Wh = h @ W[hd] (LDS-free), emit R/F1/F2 + swizzled bf16
//   Wh^T. Dispatched FIRST so they overlap the stream blocks behind them.
// Blocks [NWH, NWH+2048): adj (256 MB) -> bitmask (8 MB) via dwordx4 loads
//   and ballots, stored in ballot-native bit order:
//     word(j) = (j>>8)*8 + ((j&3)<<1) + ((j>>7)&1), bit(j) = (j>>2)&31
//   (consumer remaps; global words for any aligned j-range stay contiguous).
// ---------------------------------------------------------------------------
__global__ __launch_bounds__(256) void k_prep(
    const int* __restrict__ adj, unsigned* __restrict__ bm,
    const float* __restrict__ h, const float* __restrict__ W,
    const float* __restrict__ a1, const float* __restrict__ a2,
    unsigned short* __restrict__ whsw, float* __restrict__ R,
    float* __restrict__ F1, float* __restrict__ F2)
{
  const int tid = threadIdx.x;
  const int bx = blockIdx.x;
  const int lane = tid & 63;

  if (bx >= NWH) {
    // ---- adj -> bitmask stream ----
    const int b = bx - NWH;
    const int row = b * 4 + (tid >> 6);
    const int* ap = adj + (size_t)row * NN;
    unsigned* bp = bm + (size_t)row * 256;

    for (int it = 0; it < 8; ++it) {
      ix4 v[4];
#pragma unroll
      for (int u = 0; u < 4; ++u)
        v[u] = *(const ix4*)(ap + (it * 4 + u) * 256 + lane * 4);
#pragma unroll
      for (int u = 0; u < 4; ++u) {
        unsigned long long b0 = __ballot(v[u][0] != 0);
        unsigned long long b1 = __ballot(v[u][1] != 0);
        unsigned long long b2 = __ballot(v[u][2] != 0);
        unsigned long long b3 = __ballot(v[u][3] != 0);
        unsigned x0 = (lane & 1) ? (unsigned)(b0 >> 32) : (unsigned)b0;
        unsigned x1 = (lane & 1) ? (unsigned)(b1 >> 32) : (unsigned)b1;
        unsigned x2 = (lane & 1) ? (unsigned)(b2 >> 32) : (unsigned)b2;
        unsigned x3 = (lane & 1) ? (unsigned)(b3 >> 32) : (unsigned)b3;
        unsigned y0 = (lane & 2) ? x1 : x0;
        unsigned y1 = (lane & 2) ? x3 : x2;
        unsigned z  = (lane & 4) ? y1 : y0;
        if (lane < 8) bp[(it * 4 + u) * 8 + lane] = z;
      }
    }
    return;
  }

  // ---- Wh part ----
  const int hd = bx >> 7;
  const int i0 = (bx & 127) << 6;           // 64 rows per block
  const int w = tid >> 6, o = tid & 63;     // wave w: rows ibase..+15, col o
  const int ibase = i0 + w * 16;

  float acc[16];
#pragma unroll
  for (int m = 0; m < 16; ++m) acc[m] = 0.f;

  const float* hp = h + (size_t)ibase * 256;
  const float* Wp = W + hd * (256 * 64) + o;   // W[k][o], stride 64
  for (int k4 = 0; k4 < 64; ++k4) {
    float w0 = Wp[(k4 * 4 + 0) * 64];
    float w1 = Wp[(k4 * 4 + 1) * 64];
    float w2 = Wp[(k4 * 4 + 2) * 64];
    float w3 = Wp[(k4 * 4 + 3) * 64];
#pragma unroll
    for (int m = 0; m < 16; ++m) {
      fx4 hv = *(const fx4*)(hp + m * 256 + k4 * 4);
      acc[m] += hv[0] * w0 + hv[1] * w1 + hv[2] * w2 + hv[3] * w3;
    }
  }

  const float a1v = a1[hd * 64 + o], a2v = a2[hd * 64 + o];
#pragma unroll
  for (int m = 0; m < 16; ++m) {
    float s1 = acc[m] * a1v, s2 = acc[m] * a2v;
#pragma unroll
    for (int d = 1; d < 64; d <<= 1) {
      s1 += __shfl_xor(s1, d);
      s2 += __shfl_xor(s2, d);
    }
    if (o == 0) {
      int ix = hd * NN + ibase + m;
      R[ix]  = __builtin_amdgcn_exp2f(-0.8f * s1 * LOG2E);
      F1[ix] = __builtin_amdgcn_exp2f(s2 * LOG2E);
      F2[ix] = __builtin_amdgcn_exp2f(0.2f * s2 * LOG2E);
    }
  }

  size_t base = (size_t)hd * 524288 + (size_t)((i0 >> 5) + (w >> 1)) * 2048 +
                (size_t)(o >> 4) * 512;
  int ln0 = (o & 15) + 16 * ((w & 1) * 2);
  ushort8 pk0, pk1;
#pragma unroll
  for (int m = 0; m < 8; ++m) {
    pk0[m] = __builtin_bit_cast(unsigned short, (__bf16)acc[m]);
    pk1[m] = __builtin_bit_cast(unsigned short, (__bf16)acc[m + 8]);
  }
  *(ushort8*)(whsw + base + (size_t)ln0 * 8) = pk0;
  *(ushort8*)(whsw + base + (size_t)(ln0 + 16) * 8) = pk1;
}

// ---------------------------------------------------------------------------
// Kernel 2: masked unnormalized softmax + PV MFMA (R8 structure, new mask
// remap for the ballot-native bit layout).
// Grid: 1024 blocks = 256 row-tiles (32 rows) x 4 j-chunks (2048);
// ci = (bx&7)>>1 pins each chunk's whsw slice to an XCD pair (L2-resident).
// q = max(F1_j, r_i*F2_j) masked; rowsum via a 5th MFMA (all-ones B).
// ---------------------------------------------------------------------------
struct Tile {
  fx4 f1a, f1b, f2a, f2b;   // F1/F2 slices (per lane group g)
  bf16x8 b0, b1, b2, b3;    // Wh^T B-fragments
  unsigned m[2][4];         // mask words [rowset][c], c = j&3
};

__device__ __forceinline__ void load_tile(Tile& t, const float* F1p,
                                          const float* F2p,
                                          const unsigned short* wp,
                                          const unsigned* bml, int il, int jb)
{
  t.f1a = *(const fx4*)(F1p + jb);
  t.f1b = *(const fx4*)(F1p + jb + 4);
  t.f2a = *(const fx4*)(F2p + jb);
  t.f2b = *(const fx4*)(F2p + jb + 4);
  const unsigned short* wq = wp + (size_t)(jb >> 5) * 2048;
  t.b0 = *(const bf16x8*)(wq);
  t.b1 = *(const bf16x8*)(wq + 512);
  t.b2 = *(const bf16x8*)(wq + 1024);
  t.b3 = *(const bf16x8*)(wq + 1536);
  const int wbase = (jb >> 8) * 8 + ((jb >> 7) & 1);
#pragma unroll
  for (int rs = 0; rs < 2; ++rs)
#pragma unroll
    for (int c = 0; c < 4; ++c)
      t.m[rs][c] = bml[(wbase + 2 * c) * 33 + rs * 16 + il];
}

__device__ __forceinline__ void compute_tile(const Tile& t, const float* Rr,
                                             int g, int tph,
                                             const bf16x8& ones,
                                             fx4 acc[2][4], fx4* accS)
{
  const int s0 = tph * 8 + 2 * g;          // runtime base bit for this tile
#pragma unroll
  for (int rs = 0; rs < 2; ++rs) {
    unsigned sm0 = t.m[rs][0] >> s0;
    unsigned sm1 = t.m[rs][1] >> s0;
    unsigned sm2 = t.m[rs][2] >> s0;
    unsigned sm3 = t.m[rs][3] >> s0;
    float p[8];
#pragma unroll
    for (int e = 0; e < 8; ++e) {
      float f1 = (e < 4) ? t.f1a[e] : t.f1b[e - 4];
      float f2 = (e < 4) ? t.f2a[e] : t.f2b[e - 4];
      float pm = fmaxf(f1, Rr[rs] * f2);   // ∝ exp(leakyrelu(es+ed))
      unsigned smc = ((e & 3) == 0) ? sm0 : ((e & 3) == 1) ? sm1
                   : ((e & 3) == 2) ? sm2 : sm3;
      unsigned keep = (unsigned)(((int)(smc << (31 - (e >> 2)))) >> 31);
      p[e] = __builtin_bit_cast(float,
                 __builtin_bit_cast(unsigned, pm) & keep);
    }
    bf16x8 af;
#pragma unroll
    for (int e = 0; e < 8; ++e) af[e] = (__bf16)p[e];
    acc[rs][0] = __builtin_amdgcn_mfma_f32_16x16x32_bf16(af, t.b0, acc[rs][0], 0, 0, 0);
    acc[rs][1] = __builtin_amdgcn_mfma_f32_16x16x32_bf16(af, t.b1, acc[rs][1], 0, 0, 0);
    acc[rs][2] = __builtin_amdgcn_mfma_f32_16x16x32_bf16(af, t.b2, acc[rs][2], 0, 0, 0);
    acc[rs][3] = __builtin_amdgcn_mfma_f32_16x16x32_bf16(af, t.b3, acc[rs][3], 0, 0, 0);
    accS[rs] = __builtin_amdgcn_mfma_f32_16x16x32_bf16(af, ones, accS[rs], 0, 0, 0);
  }
}

__global__ __launch_bounds__(256) void k_attn(
    const unsigned* __restrict__ bm, const unsigned short* __restrict__ whsw,
    const float* __restrict__ Rg, const float* __restrict__ F1g,
    const float* __restrict__ F2g, float* __restrict__ pacc,
    float* __restrict__ psum)
{
  __shared__ unsigned bml[(CHUNK / 32) * 33];   // padded [w*33+row]: 8.25 KiB
  const int tid = threadIdx.x;
  const int lane = tid & 63;
  const int hd = tid >> 6;                 // wave = head
  const int bx = blockIdx.x;
  const int xcd = bx & 7;
  const int ci = xcd >> 1;                 // chunk pinned to an XCD pair
  const int rt = ((bx >> 3) << 1) | (xcd & 1);
  const int i0 = rt << 5;                  // 32 rows
  const int j0 = ci * CHUNK;
  const int il = lane & 15;
  const int g = lane >> 4;

  // ---- stage bitmask slice (8 KB) into LDS; pad 33 -> conflict-free ----
  for (int it = 0; it < 8; ++it) {
    int idx = it * 256 + tid;              // 2048 words
    int r = idx >> 6, w = idx & 63;        // w = lane -> coalesced global read
    unsigned v = bm[(size_t)(i0 + r) * 256 + (j0 >> 5) + w];
    bml[w * 33 + r] = v;                   // banks (w+r)%32: all distinct
  }
  __syncthreads();

  // ---- masked softmax + PV ----
  float Rr[2];
#pragma unroll
  for (int rs = 0; rs < 2; ++rs)
    Rr[rs] = Rg[hd * NN + i0 + rs * 16 + il];
  const float* F1p = F1g + hd * NN + j0 + g * 8;
  const float* F2p = F2g + hd * NN + j0 + g * 8;
  const unsigned short* wp = whsw + (size_t)hd * 524288 +
                             (size_t)(j0 >> 5) * 2048 + (size_t)lane * 8;
  bf16x8 ones;
#pragma unroll
  for (int e = 0; e < 8; ++e) ones[e] = (__bf16)1.0f;

  fx4 acc[2][4] = {};
  fx4 accS[2] = {};

  Tile t0, t1;
  load_tile(t0, F1p, F2p, wp, bml, il, 0);
  for (int jb = 0; jb < CHUNK; jb += 64) {
    int tp = (jb >> 5) & 3;
    load_tile(t1, F1p, F2p, wp, bml, il, jb + 32);
    compute_tile(t0, Rr, g, tp, ones, acc, accS);
    if (jb + 64 < CHUNK) load_tile(t0, F1p, F2p, wp, bml, il, jb + 64);
    compute_tile(t1, Rr, g, (tp + 1) & 3, ones, acc, accS);
  }

  // partial row sums (all columns of accS equal the rowsum)
#pragma unroll
  for (int rs = 0; rs < 2; ++rs) {
    if (il == 0) {
#pragma unroll
      for (int r = 0; r < 4; ++r)
        psum[(size_t)(ci * NHEADS + hd) * NN + i0 + rs * 16 + g * 4 + r] =
            accS[rs][r];
    }
  }

  // raw accumulator store. C/D: col f = lane&15, row i = 4*(lane>>4)+r
  float* pc = pacc + (size_t)ci * NN * 256;
#pragma unroll
  for (int rs = 0; rs < 2; ++rs)
#pragma unroll
    for (int r = 0; r < 4; ++r)
#pragma unroll
      for (int ft = 0; ft < 4; ++ft)
        pc[(size_t)(i0 + rs * 16 + g * 4 + r) * 256 + hd * 64 + ft * 16 + il] =
            acc[rs][ft][r];
}

// ---------------------------------------------------------------------------
// Kernel 3: combine chunks -> normalize -> ELU -> out = att @ fc_w^T + fc_b
// 256 blocks x 32 rows.
// ---------------------------------------------------------------------------
__global__ __launch_bounds__(256) void k_fc(
    const float* __restrict__ pacc, const float* __restrict__ psum,
    const float* __restrict__ fcw, const float* __restrict__ fcb,
    float* __restrict__ out)
{
  __shared__ float ws[256 * 65];    // fcw transposed: ws[c*65 + o]
  __shared__ float ash[32 * 260];   // combined att rows
  __shared__ float inv[32 * 4];
  const int tid = threadIdx.x;
  const int i0 = blockIdx.x * 32;

  for (int idx = tid; idx < 64 * 256; idx += 256) {
    int o = idx >> 8, c = idx & 255;
    ws[c * 65 + o] = fcw[idx];
  }
  if (tid < 128) {
    int m = tid >> 2, hh = tid & 3;
    float s = 0.f;
#pragma unroll
    for (int ci = 0; ci < NCHUNK; ++ci)
      s += psum[(size_t)(ci * NHEADS + hh) * NN + i0 + m];
    inv[m * 4 + hh] = 1.0f / s;
  }
  __syncthreads();

  for (int idx = tid; idx < 32 * 64; idx += 256) {
    int m = idx >> 6, q = idx & 63;
    int hh = q >> 4;
    size_t off = (size_t)(i0 + m) * 256 + q * 4;
    fx4 v = {};
#pragma unroll
    for (int ci = 0; ci < NCHUNK; ++ci) {
      fx4 a = *(const fx4*)(pacc + (size_t)ci * NN * 256 + off);
      v[0] += a[0]; v[1] += a[1]; v[2] += a[2]; v[3] += a[3];
    }
    float iv = inv[m * 4 + hh];
#pragma unroll
    for (int j = 0; j < 4; ++j) {
      float x = v[j] * iv;
      x = (x > 0.f) ? x : (__builtin_amdgcn_exp2f(x * LOG2E) - 1.0f);  // ELU
      ash[m * 260 + q * 4 + j] = x;
    }
  }
  __syncthreads();

  const int w = tid >> 6, o = tid & 63;
  float acc[8];
#pragma unroll
  for (int m = 0; m < 8; ++m) acc[m] = 0.f;

  for (int c4 = 0; c4 < 64; ++c4) {
    float w0 = ws[(c4 * 4 + 0) * 65 + o];
    float w1 = ws[(c4 * 4 + 1) * 65 + o];
    float w2 = ws[(c4 * 4 + 2) * 65 + o];
    float w3 = ws[(c4 * 4 + 3) * 65 + o];
#pragma unroll
    for (int m = 0; m < 8; ++m) {
      fx4 hv = *(const fx4*)(&ash[(w * 8 + m) * 260 + c4 * 4]);
      acc[m] += hv[0] * w0 + hv[1] * w1 + hv[2] * w2 + hv[3] * w3;
    }
  }
  const float bo = fcb[o];
#pragma unroll
  for (int m = 0; m < 8; ++m)
    out[(size_t)(i0 + w * 8 + m) * 64 + o] = acc[m] + bo;
}

extern "C" void kernel_launch(void* const* d_in, const int* in_sizes, int n_in,
                              void* d_out, int out_size, void* d_ws, size_t ws_size,
                              hipStream_t stream) {
  (void)in_sizes; (void)n_in; (void)out_size; (void)ws_size;
  const float* h   = (const float*)d_in[0];
  const int*   adj = (const int*)d_in[1];
  const float* W   = (const float*)d_in[2];
  const float* a1  = (const float*)d_in[3];
  const float* a2  = (const float*)d_in[4];
  const float* fcw = (const float*)d_in[5];
  const float* fcb = (const float*)d_in[6];
  float* out = (float*)d_out;

  char* base = (char*)d_ws;
  unsigned short* whsw = (unsigned short*)base;            // 4 MiB
  float* R  = (float*)(base + (4u << 20));                 // 128 KiB each
  float* F1 = (float*)(base + (4u << 20) + (128u << 10));
  float* F2 = (float*)(base + (4u << 20) + (256u << 10));
  unsigned* bmask = (unsigned*)(base + (5u << 20));        // 8 MiB
  float* pacc = (float*)(base + (13u << 20));              // 32 MiB
  float* psum = (float*)(base + (45u << 20));              // 512 KiB

  k_prep<<<dim3(NWH + 2048), dim3(256), 0, stream>>>(adj, bmask, h, W, a1, a2,
                                                     whsw, R, F1, F2);
  k_attn<<<dim3(1024), dim3(256), 0, stream>>>(bmask, whsw, R, F1, F2, pacc, psum);
  k_fc<<<dim3(256), dim3(256), 0, stream>>>(pacc, psum, fcw, fcb, out);
}